// Round 7
// baseline (658.262 us; speedup 1.0000x reference)
//
#include <hip/hip_runtime.h>

// ---------------------------------------------------------------------------
// Fused Linear + SimPO loss on MI355X (gfx950)
// M = 4096 tokens, V = 32000, K = 2048
// GEMM R7: BM=256, BN=128, BK=32, 8 waves (64x64 out each), LDS ring of
// 3 x 24KB buffers -> 2 blocks/CU (16 waves/CU). One barrier per K-tile:
// {reads(t); stage(t+2); MFMA; vmcnt(3); barrier}. Drain-before-barrier.
// T2 swizzle ((row>>1)&3), T5 setprio, bijective XCD swizzle, fused
// sum-exp epilogue.
// ---------------------------------------------------------------------------

typedef short bf16x8 __attribute__((ext_vector_type(8)));
typedef float f32x4 __attribute__((ext_vector_type(4)));

#define IGNORE_INDEX (-100)
#define BETA_ 0.1f
#define GAMMA_ 0.5f

#define M_TOK 4096
#define V_DIM 32000
#define K_DIM 2048
#define NVT 250          // V / 128
#define NMT 16           // M / 256
#define NT2 64           // K / 32  (K-tiles)
#define BUFSZ 24576      // (256 + 128) * 32 * 2B

__device__ inline unsigned short f2bf(float f) {   // RNE fp32 -> bf16
    unsigned u = __float_as_uint(f);
    return (unsigned short)((u + 0x7FFFu + ((u >> 16) & 1u)) >> 16);
}

// -------- fp32 -> bf16 conversion ------------------------------------------
__global__ void __launch_bounds__(256) cvt_kernel(const float* __restrict__ src,
                                                  unsigned short* __restrict__ dst) {
    size_t i = ((size_t)blockIdx.x * 256 + threadIdx.x) * 4;
    float4 v = *reinterpret_cast<const float4*>(src + i);
    ushort4 o;
    o.x = f2bf(v.x); o.y = f2bf(v.y); o.z = f2bf(v.z); o.w = f2bf(v.w);
    *reinterpret_cast<ushort4*>(dst + i) = o;
}

// -------- exact fp32 target logit: one wave per token ----------------------
__global__ void __launch_bounds__(256) zt_kernel(const float* __restrict__ X,
                                                 const float* __restrict__ W,
                                                 const float* __restrict__ bias,
                                                 const int* __restrict__ target,
                                                 float* __restrict__ zt) {
    int token = blockIdx.x * 4 + (threadIdx.x >> 6);
    int lane = threadIdx.x & 63;
    int t = target[token];
    int tt = (t < 0) ? 0 : t;
    const float4* xr = reinterpret_cast<const float4*>(X + (size_t)token * K_DIM);
    const float4* wr = reinterpret_cast<const float4*>(W + (size_t)tt * K_DIM);
    float s = 0.f;
    #pragma unroll
    for (int j = 0; j < 8; ++j) {
        float4 a = xr[lane + j * 64];
        float4 b = wr[lane + j * 64];
        s += a.x * b.x + a.y * b.y + a.z * b.z + a.w * b.w;
    }
    #pragma unroll
    for (int m = 1; m < 64; m <<= 1) s += __shfl_xor(s, m, 64);
    if (lane == 0) zt[token] = s + bias[tt];
}

// -------- 256x128 tri-buffered bf16 GEMM with fused sum-exp epilogue -------
// LDS buffer (3-ring, stride 24576): A @0 ([256][32] bf16, 16KB),
// B @16384 ([128][32] bf16, 8KB). Row stride 64B.
// Swizzle: 16B slot c of row holds global k-slot (c ^ ((row>>1)&3)).
#define GLL(g, l) __builtin_amdgcn_global_load_lds( \
    (const __attribute__((address_space(1))) void*)(g), \
    (__attribute__((address_space(3))) void*)(l), 16, 0, 0)

__global__ void __launch_bounds__(512, 4) gemm_lse_kernel(
    const unsigned short* __restrict__ Xb,   // [4096][2048] bf16
    const unsigned short* __restrict__ Wb,   // [32000][2048] bf16
    const float* __restrict__ bias,          // [32000]
    float* __restrict__ partials) {          // [NVT][4096] sum-exp partials
    __shared__ char lds[3 * BUFSZ];          // 73728 B -> 2 blocks/CU

    const int tid = threadIdx.x;
    const int wid = tid >> 6;
    const int lane = tid & 63;
    const int r = lane & 15, g = lane >> 4;
    const int wm = wid >> 1, wn = wid & 1;   // 4x2 wave grid, 64x64 out each

    // bijective XCD-chunked swizzle: 4000 = 8 * 500, mt fastest inside chunk
    int nb = (blockIdx.x & 7) * 500 + (blockIdx.x >> 3);
    const int vt = nb >> 4;                  // 0..249
    const int mt = nb & 15;                  // 0..15

    // staging: thread covers row tid>>2 (A also +128), 16B slot tid&3,
    // inverse-swizzled source slot = (tid&3) ^ ((srow>>1)&3)
    const int srow = tid >> 2;
    const int scol = ((tid & 3) ^ ((srow >> 1) & 3)) * 8;
    const unsigned short* aS0 = Xb + (size_t)(mt * 256 + srow) * K_DIM + scol;
    const unsigned short* aS1 = aS0 + (size_t)128 * K_DIM;
    const unsigned short* bS0 = Wb + (size_t)(vt * 128 + srow) * K_DIM + scol;

    char* sbase = lds + wid * 1024;          // wave-uniform staging base
    // swizzled ds_read per-lane byte offsets ((row>>1)&3 == (r>>1)&3 since
    // wm*64, wn*64, frag*16 are all multiples of 16)
    const int vA = (wm * 64 + r) * 64 + ((g ^ ((r >> 1) & 3)) << 4);
    const int vB = 16384 + (wn * 64 + r) * 64 + ((g ^ ((r >> 1) & 3)) << 4);

    f32x4 acc[4][4] = {};
    bf16x8 af[4], bf[4];

#define BARX do { \
    asm volatile("" ::: "memory"); \
    __builtin_amdgcn_s_barrier(); \
    asm volatile("" ::: "memory"); \
} while (0)

#define VM3 asm volatile("s_waitcnt vmcnt(3)" ::: "memory")
#define VM0 asm volatile("s_waitcnt vmcnt(0)" ::: "memory")

#define STAGE(bofs) do { \
    GLL(aS0, sbase + (bofs)); \
    GLL(aS1, sbase + (bofs) + 8192); \
    GLL(bS0, sbase + (bofs) + 16384); \
    aS0 += 32; aS1 += 32; bS0 += 32; \
} while (0)

#define RDALL(bofs) do { \
    _Pragma("unroll") \
    for (int n2 = 0; n2 < 4; ++n2) \
        bf[n2] = *(const bf16x8*)(lds + (bofs) + vB + n2 * 1024); \
    _Pragma("unroll") \
    for (int m2 = 0; m2 < 4; ++m2) \
        af[m2] = *(const bf16x8*)(lds + (bofs) + vA + m2 * 1024); \
} while (0)

#define MFMA16() do { \
    __builtin_amdgcn_s_setprio(1); \
    _Pragma("unroll") \
    for (int m2 = 0; m2 < 4; ++m2) { \
        _Pragma("unroll") \
        for (int n2 = 0; n2 < 4; ++n2) \
            acc[m2][n2] = __builtin_amdgcn_mfma_f32_16x16x32_bf16( \
                af[m2], bf[n2], acc[m2][n2], 0, 0, 0); \
    } \
    __builtin_amdgcn_s_setprio(0); \
} while (0)

    // ---- prologue: stage tiles 0,1 into buffers 0,1; ensure t0 done -------
    STAGE(0);
    STAGE(BUFSZ);
    VM3;                 // 6 outstanding -> oldest 3 (tile 0) complete
    BARX;

    int cur = 0, nxt = BUFSZ, nx2 = 2 * BUFSZ;
    #pragma unroll 1
    for (int t = 0; t < NT2 - 2; ++t) {
        RDALL(cur);
        STAGE(nx2);      // stage tile t+2 into the ring slot holding t-1
        MFMA16();
        VM3;             // tile t+1 GLLs complete before publishing barrier
        BARX;
        int tmp = cur; cur = nxt; nxt = nx2; nx2 = tmp;
    }
    // t = 62: no stage; drain everything (tile 63) before its reads
    RDALL(cur);
    MFMA16();
    VM0;
    BARX;
    // t = 63
    RDALL(nxt);
    MFMA16();

    // ---- epilogue: bias + exp + row-sum over this block's 128 cols -------
    float bb[4];
    #pragma unroll
    for (int nf = 0; nf < 4; ++nf)
        bb[nf] = bias[vt * 128 + wn * 64 + nf * 16 + r];

    __syncthreads();
    float* red = reinterpret_cast<float*>(lds);  // [2 wn][256 rows]
    #pragma unroll
    for (int mf = 0; mf < 4; ++mf) {
        #pragma unroll
        for (int i = 0; i < 4; ++i) {
            float s = 0.f;
            #pragma unroll
            for (int nf = 0; nf < 4; ++nf)
                s += __expf(acc[mf][nf][i] + bb[nf]);
            s += __shfl_xor(s, 1, 64);
            s += __shfl_xor(s, 2, 64);
            s += __shfl_xor(s, 4, 64);
            s += __shfl_xor(s, 8, 64);       // sum over 16 cols in group
            if (r == 0) red[wn * 256 + wm * 64 + mf * 16 + g * 4 + i] = s;
        }
    }
    __syncthreads();
    if (tid < 256) {
        float tot = red[tid] + red[256 + tid];
        partials[(size_t)vt * M_TOK + mt * 256 + tid] = tot;
    }
}

// -------- combine partials -> per-token logp -------------------------------
__global__ void __launch_bounds__(256) lse_kernel(const float* __restrict__ partials,
                                                  const float* __restrict__ zt,
                                                  float* __restrict__ logp) {
    int token = blockIdx.x * 256 + threadIdx.x;
    float s = 0.f;
    for (int v = 0; v < NVT; ++v) s += partials[(size_t)v * M_TOK + token];
    logp[token] = zt[token] - logf(s);
}

// -------- final SimPO scalar ----------------------------------------------
__global__ void __launch_bounds__(512) loss_kernel(const float* __restrict__ logp,
                                                   const int* __restrict__ target,
                                                   float* __restrict__ out) {
    __shared__ float ss[8], sc[8];
    int wid = threadIdx.x >> 6, lane = threadIdx.x & 63;
    float s = 0.f, cnt = 0.f;
    #pragma unroll
    for (int j = 0; j < 8; ++j) {
        int token = wid * 512 + lane + j * 64;
        if (target[token] != IGNORE_INDEX) { s += logp[token]; cnt += 1.f; }
    }
    #pragma unroll
    for (int m = 1; m < 64; m <<= 1) {
        s += __shfl_xor(s, m, 64);
        cnt += __shfl_xor(cnt, m, 64);
    }
    if (lane == 0) { ss[wid] = s; sc[wid] = cnt; }
    __syncthreads();
    if (threadIdx.x == 0) {
        float csum = 0.f, ccnt = 0.f;
        for (int b = 0; b < 4; ++b) { csum += ss[b]; ccnt += sc[b]; }
        float nll = -csum / ccnt;
        float pref = 0.f;
        for (int b = 0; b < 4; ++b) {
            float d = BETA_ * (ss[b] / sc[b] - ss[b + 4] / sc[b + 4]) - GAMMA_;
            float sp = (d > 0.f) ? log1pf(expf(-d)) : (-d + log1pf(expf(d)));
            pref += sp;
        }
        pref *= 0.25f;
        out[0] = nll + pref;
    }
}

// ---------------------------------------------------------------------------
extern "C" void kernel_launch(void* const* d_in, const int* in_sizes, int n_in,
                              void* d_out, int out_size, void* d_ws, size_t ws_size,
                              hipStream_t stream) {
    const float* W    = (const float*)d_in[0];
    const float* X    = (const float*)d_in[1];
    const int* target = (const int*)d_in[2];
    const float* bias = (const float*)d_in[3];
    float* out = (float*)d_out;
    char* ws = (char*)d_ws;

    // workspace layout (16B aligned), ~152 MB total
    unsigned short* Wb = (unsigned short*)(ws);                    // 131,072,000 B
    unsigned short* Xb = (unsigned short*)(ws + 131072000);        //  16,777,216 B
    float* partials    = (float*)(ws + 147849216);                 //   4,096,000 B
    float* zt          = (float*)(ws + 151945216);                 //      16,384 B
    float* logp        = (float*)(ws + 151961600);                 //      16,384 B

    cvt_kernel<<<dim3(64000), 256, 0, stream>>>(W, Wb);
    cvt_kernel<<<dim3(8192), 256, 0, stream>>>(X, Xb);
    zt_kernel<<<dim3(1024), 256, 0, stream>>>(X, W, bias, target, zt);
    gemm_lse_kernel<<<dim3(NMT * NVT), 512, 0, stream>>>(Xb, Wb, bias, partials);
    lse_kernel<<<dim3(16), 256, 0, stream>>>(partials, zt, logp);
    loss_kernel<<<dim3(1), 512, 0, stream>>>(logp, target, out);
}